// Round 1
// baseline (355.605 us; speedup 1.0000x reference)
//
#include <hip/hip_runtime.h>
#include <hip/hip_bf16.h>

#define B_ 4
#define S_ 2048
#define D_ 1024
#define H_ 16
#define DK_ 64

typedef __bf16 bf16;
typedef bf16 bf16x8 __attribute__((ext_vector_type(8)));
typedef float f32x4 __attribute__((ext_vector_type(4)));

// XOR swizzle for [rows][64-bf16] LDS tiles (128B rows, 8×16B slots):
// element offset of 16B slot `slot` in row `row`
__device__ __forceinline__ int swz8(int row, int slot) {
    return row * 64 + (((slot) ^ (row & 7)) << 3);
}
// scalar element (row, col) under the same swizzle
__device__ __forceinline__ int swz_elem(int row, int col) {
    return row * 64 + ((((col >> 3)) ^ (row & 7)) << 3) + (col & 7);
}

// ---------------- weight transpose + cast: dst[n][k] = (bf16) src[k][n] ----------------
__global__ void transpose_w_kernel(const float* wq, const float* wk, const float* wv, const float* wo,
                                   bf16* wqkvT, bf16* woT) {
    __shared__ float t[32][33];
    const int z = blockIdx.z;
    const float* src = (z == 0) ? wq : (z == 1) ? wk : (z == 2) ? wv : wo;
    bf16* dst = (z < 3) ? (wqkvT + (size_t)z * 1024 * 1024) : woT;
    const int n0 = blockIdx.x * 32, k0 = blockIdx.y * 32;
    const int tx = threadIdx.x, ty = threadIdx.y;
#pragma unroll
    for (int j = 0; j < 4; ++j)
        t[ty + j * 8][tx] = src[(size_t)(k0 + ty + j * 8) * 1024 + n0 + tx];
    __syncthreads();
#pragma unroll
    for (int j = 0; j < 4; ++j)
        dst[(size_t)(n0 + ty + j * 8) * 1024 + k0 + tx] = (bf16)t[tx][ty + j * 8];
}

// ---------------- GEMM: C[M,N] = A[M,K] @ Bt[N,K]^T, bf16 MFMA, fp32 accum ----------------
// MODE 0: A is fp32 (x), epilogue scatters bf16 into Q/K/V [b,h,s,dk] (N=3072 concat)
// MODE 1: A is bf16 (ctx), epilogue writes fp32 C to o0
template <int MODE>
__global__ __launch_bounds__(256) void gemm_kernel(const void* Av, const bf16* Bt,
                                                   void* o0, void* o1, void* o2,
                                                   int M, int N, int K) {
    __shared__ __align__(16) bf16 As[128 * 64];
    __shared__ __align__(16) bf16 Bs[128 * 64];
    const int tid = threadIdx.x;
    const int lane = tid & 63;
    const int w = tid >> 6;
    const int wm = w >> 1, wn = w & 1;
    const int g = lane >> 4, r16 = lane & 15;
    const int m0 = blockIdx.y * 128, n0 = blockIdx.x * 128;
    const int rS = tid >> 3, cS = tid & 7;

    f32x4 acc[4][4] = {};

    for (int kt = 0; kt < K; kt += 64) {
        if (MODE == 0) {
            const float* A = (const float*)Av;
#pragma unroll
            for (int p = 0; p < 4; ++p) {
                int r = p * 32 + rS;
                const float4* src = (const float4*)(A + (size_t)(m0 + r) * K + kt + cS * 8);
                float4 f0 = src[0], f1 = src[1];
                bf16x8 v;
                v[0] = (bf16)f0.x; v[1] = (bf16)f0.y; v[2] = (bf16)f0.z; v[3] = (bf16)f0.w;
                v[4] = (bf16)f1.x; v[5] = (bf16)f1.y; v[6] = (bf16)f1.z; v[7] = (bf16)f1.w;
                *(bf16x8*)&As[swz8(r, cS)] = v;
            }
        } else {
            const bf16* A = (const bf16*)Av;
#pragma unroll
            for (int p = 0; p < 4; ++p) {
                int r = p * 32 + rS;
                *(bf16x8*)&As[swz8(r, cS)] = *(const bf16x8*)(A + (size_t)(m0 + r) * K + kt + cS * 8);
            }
        }
#pragma unroll
        for (int p = 0; p < 4; ++p) {
            int r = p * 32 + rS;
            *(bf16x8*)&Bs[swz8(r, cS)] = *(const bf16x8*)(Bt + (size_t)(n0 + r) * K + kt + cS * 8);
        }
        __syncthreads();
#pragma unroll
        for (int k0 = 0; k0 < 2; ++k0) {
            bf16x8 af[4], bfr[4];
#pragma unroll
            for (int mf = 0; mf < 4; ++mf)
                af[mf] = *(const bf16x8*)&As[swz8(wm * 64 + mf * 16 + r16, 4 * k0 + g)];
#pragma unroll
            for (int nf = 0; nf < 4; ++nf)
                bfr[nf] = *(const bf16x8*)&Bs[swz8(wn * 64 + nf * 16 + r16, 4 * k0 + g)];
#pragma unroll
            for (int mf = 0; mf < 4; ++mf)
#pragma unroll
                for (int nf = 0; nf < 4; ++nf)
                    acc[mf][nf] = __builtin_amdgcn_mfma_f32_16x16x32_bf16(af[mf], bfr[nf], acc[mf][nf], 0, 0, 0);
        }
        __syncthreads();
    }

#pragma unroll
    for (int mf = 0; mf < 4; ++mf) {
#pragma unroll
        for (int nf = 0; nf < 4; ++nf) {
#pragma unroll
            for (int rr = 0; rr < 4; ++rr) {
                int row = m0 + wm * 64 + mf * 16 + 4 * g + rr;
                int col = n0 + wn * 64 + nf * 16 + r16;
                float val = acc[mf][nf][rr];
                if (MODE == 0) {
                    int seg = col >> 10, n1 = col & 1023;
                    int h = n1 >> 6, dk = n1 & 63;
                    int b = row >> 11, s = row & 2047;
                    size_t idx = (((size_t)b * H_ + h) * S_ + s) * DK_ + dk;
                    bf16 bv = (bf16)val;
                    if (seg == 0) ((bf16*)o0)[idx] = bv;
                    else if (seg == 1) ((bf16*)o1)[idx] = bv;
                    else ((bf16*)o2)[idx] = bv;
                } else {
                    ((float*)o0)[(size_t)row * N + col] = val;
                }
            }
        }
    }
}

// ---------------- V [b,h,s,dk] -> Vt [b,h,dk,s] ----------------
__global__ __launch_bounds__(256) void transpose_v_kernel(const bf16* V, bf16* Vt) {
    __shared__ __align__(16) bf16 t[64][68];
    const int st = blockIdx.x, bh = blockIdx.y;
    const int tid = threadIdx.x;
#pragma unroll
    for (int p = 0; p < 2; ++p) {
        int chunk = tid + p * 256;
        int sl = chunk >> 3, c = chunk & 7;
        bf16x8 v = *(const bf16x8*)(V + ((size_t)bh * S_ + st * 64 + sl) * DK_ + c * 8);
#pragma unroll
        for (int e = 0; e < 8; ++e) t[c * 8 + e][sl] = v[e];
    }
    __syncthreads();
#pragma unroll
    for (int p = 0; p < 4; ++p) {
        int chunk = tid + p * 256;
        int dk = chunk >> 4, sc = chunk & 15;
        ushort4 v = *(const ushort4*)&t[dk][sc * 4];
        *(ushort4*)(Vt + ((size_t)bh * DK_ + dk) * S_ + st * 64 + sc * 4) = v;
    }
}

// ---------------- causal flash attention ----------------
// grid (32 q-tiles, 64 bh); block 256 = 4 waves, wave w owns q rows [qt*64+w*16, +16)
__global__ __launch_bounds__(256) void attn_kernel(const bf16* Q, const bf16* Kb, const bf16* Vt, bf16* ctx) {
    __shared__ __align__(16) bf16 Ks[64 * 64];
    __shared__ __align__(16) bf16 Vts[64 * 64];
    __shared__ __align__(16) bf16 Ps[4 * 16 * 64];
    const int qt = blockIdx.x, bh = blockIdx.y;
    const int tid = threadIdx.x, lane = tid & 63, w = tid >> 6;
    const int g = lane >> 4, r16 = lane & 15;
    const float qscale = 0.125f * 1.44269504088896340736f;  // 1/sqrt(DK) * log2(e)

    bf16x8 qf[2];
    {
        int s_q = qt * 64 + w * 16 + r16;
        const bf16* qp = Q + ((size_t)bh * S_ + s_q) * DK_;
#pragma unroll
        for (int k0 = 0; k0 < 2; ++k0) {
            bf16x8 raw = *(const bf16x8*)(qp + (4 * k0 + g) * 8);
#pragma unroll
            for (int e = 0; e < 8; ++e) qf[k0][e] = (bf16)((float)raw[e] * qscale);
        }
    }

    float m_r[4], l_r[4];
    f32x4 acc_o[4] = {};
#pragma unroll
    for (int rr = 0; rr < 4; ++rr) { m_r[rr] = -INFINITY; l_r[rr] = 0.f; }

    const int rS = tid >> 3, cS = tid & 7;

    for (int jt = 0; jt <= qt; ++jt) {
        __syncthreads();
#pragma unroll
        for (int p = 0; p < 2; ++p) {
            int r = p * 32 + rS;
            *(bf16x8*)&Ks[swz8(r, cS)] = *(const bf16x8*)(Kb + ((size_t)bh * S_ + jt * 64 + r) * DK_ + cS * 8);
            *(bf16x8*)&Vts[swz8(r, cS)] = *(const bf16x8*)(Vt + ((size_t)bh * DK_ + r) * S_ + jt * 64 + cS * 8);
        }
        __syncthreads();

        f32x4 sacc[4] = {};
#pragma unroll
        for (int k0 = 0; k0 < 2; ++k0)
#pragma unroll
            for (int nf = 0; nf < 4; ++nf) {
                bf16x8 kf = *(const bf16x8*)&Ks[swz8(nf * 16 + r16, 4 * k0 + g)];
                sacc[nf] = __builtin_amdgcn_mfma_f32_16x16x32_bf16(qf[k0], kf, sacc[nf], 0, 0, 0);
            }

        if (jt == qt) {
#pragma unroll
            for (int nf = 0; nf < 4; ++nf)
#pragma unroll
                for (int rr = 0; rr < 4; ++rr) {
                    int keyl = nf * 16 + r16;
                    int ql = w * 16 + 4 * g + rr;
                    if (keyl > ql) sacc[nf][rr] = -INFINITY;
                }
        }

        float mnew[4], alpha[4];
#pragma unroll
        for (int rr = 0; rr < 4; ++rr) {
            float vm = fmaxf(fmaxf(sacc[0][rr], sacc[1][rr]), fmaxf(sacc[2][rr], sacc[3][rr]));
#pragma unroll
            for (int off = 8; off >= 1; off >>= 1)
                vm = fmaxf(vm, __shfl_xor(vm, off));
            mnew[rr] = fmaxf(m_r[rr], vm);
            alpha[rr] = exp2f(m_r[rr] - mnew[rr]);
            m_r[rr] = mnew[rr];
        }
#pragma unroll
        for (int nf = 0; nf < 4; ++nf)
#pragma unroll
            for (int rr = 0; rr < 4; ++rr)
                sacc[nf][rr] = exp2f(sacc[nf][rr] - mnew[rr]);
#pragma unroll
        for (int rr = 0; rr < 4; ++rr) {
            float ps = sacc[0][rr] + sacc[1][rr] + sacc[2][rr] + sacc[3][rr];
#pragma unroll
            for (int off = 8; off >= 1; off >>= 1)
                ps += __shfl_xor(ps, off);
            l_r[rr] = l_r[rr] * alpha[rr] + ps;
        }
#pragma unroll
        for (int nf2 = 0; nf2 < 4; ++nf2)
#pragma unroll
            for (int rr = 0; rr < 4; ++rr)
                acc_o[nf2][rr] *= alpha[rr];

        bf16* Pw = Ps + w * 1024;  // wave-private 16x64 tile
#pragma unroll
        for (int nf = 0; nf < 4; ++nf)
#pragma unroll
            for (int rr = 0; rr < 4; ++rr) {
                int row = 4 * g + rr, col = nf * 16 + r16;
                Pw[swz_elem(row, col)] = (bf16)sacc[nf][rr];
            }

#pragma unroll
        for (int k0 = 0; k0 < 2; ++k0) {
            bf16x8 pf = *(const bf16x8*)&Pw[swz8(r16, 4 * k0 + g)];
#pragma unroll
            for (int nf2 = 0; nf2 < 4; ++nf2) {
                bf16x8 vf = *(const bf16x8*)&Vts[swz8(nf2 * 16 + r16, 4 * k0 + g)];
                acc_o[nf2] = __builtin_amdgcn_mfma_f32_16x16x32_bf16(pf, vf, acc_o[nf2], 0, 0, 0);
            }
        }
    }

    const int b = bh >> 4, h = bh & 15;
#pragma unroll
    for (int nf2 = 0; nf2 < 4; ++nf2)
#pragma unroll
        for (int rr = 0; rr < 4; ++rr) {
            int qrow = qt * 64 + w * 16 + 4 * g + rr;
            float val = acc_o[nf2][rr] / l_r[rr];
            ctx[((size_t)b * S_ + qrow) * D_ + h * DK_ + nf2 * 16 + r16] = (bf16)val;
        }
}

extern "C" void kernel_launch(void* const* d_in, const int* in_sizes, int n_in,
                              void* d_out, int out_size, void* d_ws, size_t ws_size,
                              hipStream_t stream) {
    const float* x  = (const float*)d_in[0];
    const float* wq = (const float*)d_in[1];
    const float* wk = (const float*)d_in[2];
    const float* wv = (const float*)d_in[3];
    const float* wo = (const float*)d_in[4];

    char* ws = (char*)d_ws;
    bf16* wqkvT = (bf16*)(ws);                    // 3072*1024*2  = 6291456 B
    bf16* woT   = (bf16*)(ws + 6291456);          // 1024*1024*2  = 2097152 B
    bf16* Qb    = (bf16*)(ws + 8388608);          // 16777216 B
    bf16* Kb    = (bf16*)(ws + 25165824);         // 16777216 B
    bf16* Vb    = (bf16*)(ws + 41943040);         // 16777216 B
    bf16* Vtb   = (bf16*)(ws + 58720256);         // 16777216 B
    bf16* ctx   = (bf16*)(ws + 75497472);         // 16777216 B -> total 92274688 B

    transpose_w_kernel<<<dim3(32, 32, 4), dim3(32, 8), 0, stream>>>(wq, wk, wv, wo, wqkvT, woT);
    gemm_kernel<0><<<dim3(24, 64), 256, 0, stream>>>(x, wqkvT, Qb, Kb, Vb, 8192, 3072, 1024);
    transpose_v_kernel<<<dim3(32, 64), 256, 0, stream>>>(Vb, Vtb);
    attn_kernel<<<dim3(32, 64), 256, 0, stream>>>(Qb, Kb, Vtb, ctx);
    gemm_kernel<1><<<dim3(8, 64), 256, 0, stream>>>(ctx, woT, d_out, nullptr, nullptr, 8192, 1024, 1024);
}

// Round 2
// 250.010 us; speedup vs baseline: 1.4224x; 1.4224x over previous
//
#include <hip/hip_runtime.h>
#include <hip/hip_bf16.h>
#include <math.h>

#define B_ 4
#define S_ 2048
#define D_ 1024
#define H_ 16
#define DK_ 64

typedef __bf16 bf16;
typedef bf16 bf16x8 __attribute__((ext_vector_type(8)));
typedef float f32x4 __attribute__((ext_vector_type(4)));
typedef float f32x16 __attribute__((ext_vector_type(16)));

// XOR swizzle for [rows][64-bf16] LDS tiles (128B rows, 8x16B slots)
__device__ __forceinline__ int swz8(int row, int slot) {
    return row * 64 + ((slot ^ (row & 7)) << 3);
}
__device__ __forceinline__ unsigned packbf(float a, float b) {
    union { bf16 h[2]; unsigned u; } x;
    x.h[0] = (bf16)a; x.h[1] = (bf16)b;
    return x.u;
}

// ---------------- weight transpose + cast: dst[n][k] = (bf16) src[k][n] ----------------
__global__ void transpose_w_kernel(const float* wq, const float* wk, const float* wv, const float* wo,
                                   bf16* wqkvT, bf16* woT) {
    __shared__ float t[32][33];
    const int z = blockIdx.z;
    const float* src = (z == 0) ? wq : (z == 1) ? wk : (z == 2) ? wv : wo;
    bf16* dst = (z < 3) ? (wqkvT + (size_t)z * 1024 * 1024) : woT;
    const int n0 = blockIdx.x * 32, k0 = blockIdx.y * 32;
    const int tx = threadIdx.x, ty = threadIdx.y;
#pragma unroll
    for (int j = 0; j < 4; ++j)
        t[ty + j * 8][tx] = src[(size_t)(k0 + ty + j * 8) * 1024 + n0 + tx];
    __syncthreads();
#pragma unroll
    for (int j = 0; j < 4; ++j)
        dst[(size_t)(n0 + ty + j * 8) * 1024 + k0 + tx] = (bf16)t[tx][ty + j * 8];
}

// ---------------- GEMM: C[M,N] = A[M,K] @ Bt[N,K]^T, bf16 MFMA, fp32 accum ----------------
template <int MODE>
__global__ __launch_bounds__(256) void gemm_kernel(const void* Av, const bf16* Bt,
                                                   void* o0, void* o1, void* o2,
                                                   int M, int N, int K) {
    __shared__ __align__(16) bf16 As[128 * 64];
    __shared__ __align__(16) bf16 Bs[128 * 64];
    const int tid = threadIdx.x;
    const int lane = tid & 63;
    const int w = tid >> 6;
    const int wm = w >> 1, wn = w & 1;
    const int g = lane >> 4, r16 = lane & 15;
    const int m0 = blockIdx.y * 128, n0 = blockIdx.x * 128;
    const int rS = tid >> 3, cS = tid & 7;

    f32x4 acc[4][4] = {};

    for (int kt = 0; kt < K; kt += 64) {
        if (MODE == 0) {
            const float* A = (const float*)Av;
#pragma unroll
            for (int p = 0; p < 4; ++p) {
                int r = p * 32 + rS;
                const float4* src = (const float4*)(A + (size_t)(m0 + r) * K + kt + cS * 8);
                float4 f0 = src[0], f1 = src[1];
                bf16x8 v;
                v[0] = (bf16)f0.x; v[1] = (bf16)f0.y; v[2] = (bf16)f0.z; v[3] = (bf16)f0.w;
                v[4] = (bf16)f1.x; v[5] = (bf16)f1.y; v[6] = (bf16)f1.z; v[7] = (bf16)f1.w;
                *(bf16x8*)&As[swz8(r, cS)] = v;
            }
        } else {
            const bf16* A = (const bf16*)Av;
#pragma unroll
            for (int p = 0; p < 4; ++p) {
                int r = p * 32 + rS;
                *(bf16x8*)&As[swz8(r, cS)] = *(const bf16x8*)(A + (size_t)(m0 + r) * K + kt + cS * 8);
            }
        }
#pragma unroll
        for (int p = 0; p < 4; ++p) {
            int r = p * 32 + rS;
            *(bf16x8*)&Bs[swz8(r, cS)] = *(const bf16x8*)(Bt + (size_t)(n0 + r) * K + kt + cS * 8);
        }
        __syncthreads();
#pragma unroll
        for (int k0 = 0; k0 < 2; ++k0) {
            bf16x8 af[4], bfr[4];
#pragma unroll
            for (int mf = 0; mf < 4; ++mf)
                af[mf] = *(const bf16x8*)&As[swz8(wm * 64 + mf * 16 + r16, 4 * k0 + g)];
#pragma unroll
            for (int nf = 0; nf < 4; ++nf)
                bfr[nf] = *(const bf16x8*)&Bs[swz8(wn * 64 + nf * 16 + r16, 4 * k0 + g)];
#pragma unroll
            for (int mf = 0; mf < 4; ++mf)
#pragma unroll
                for (int nf = 0; nf < 4; ++nf)
                    acc[mf][nf] = __builtin_amdgcn_mfma_f32_16x16x32_bf16(af[mf], bfr[nf], acc[mf][nf], 0, 0, 0);
        }
        __syncthreads();
    }

#pragma unroll
    for (int mf = 0; mf < 4; ++mf) {
#pragma unroll
        for (int nf = 0; nf < 4; ++nf) {
#pragma unroll
            for (int rr = 0; rr < 4; ++rr) {
                int row = m0 + wm * 64 + mf * 16 + 4 * g + rr;
                int col = n0 + wn * 64 + nf * 16 + r16;
                float val = acc[mf][nf][rr];
                if (MODE == 0) {
                    int seg = col >> 10, n1 = col & 1023;
                    int h = n1 >> 6, dk = n1 & 63;
                    int b = row >> 11, s = row & 2047;
                    size_t idx = (((size_t)b * H_ + h) * S_ + s) * DK_ + dk;
                    bf16 bv = (bf16)val;
                    if (seg == 0) ((bf16*)o0)[idx] = bv;
                    else if (seg == 1) ((bf16*)o1)[idx] = bv;
                    else ((bf16*)o2)[idx] = bv;
                } else {
                    ((float*)o0)[(size_t)row * N + col] = val;
                }
            }
        }
    }
}

// ---------------- V [b,h,s,dk] -> Vt [b,h,dk,s] ----------------
__global__ __launch_bounds__(256) void transpose_v_kernel(const bf16* V, bf16* Vt) {
    __shared__ __align__(16) bf16 t[64][68];
    const int st = blockIdx.x, bh = blockIdx.y;
    const int tid = threadIdx.x;
#pragma unroll
    for (int p = 0; p < 2; ++p) {
        int chunk = tid + p * 256;
        int sl = chunk >> 3, c = chunk & 7;
        bf16x8 v = *(const bf16x8*)(V + ((size_t)bh * S_ + st * 64 + sl) * DK_ + c * 8);
#pragma unroll
        for (int e = 0; e < 8; ++e) t[c * 8 + e][sl] = v[e];
    }
    __syncthreads();
#pragma unroll
    for (int p = 0; p < 4; ++p) {
        int chunk = tid + p * 256;
        int dk = chunk >> 4, sc = chunk & 15;
        ushort4 v = *(const ushort4*)&t[dk][sc * 4];
        *(ushort4*)(Vt + ((size_t)bh * DK_ + dk) * S_ + st * 64 + sc * 4) = v;
    }
}

// ---------------- causal flash attention, swapped-operand 32x32x16 ----------------
// grid (8 qtiles, 64 bh); block 512 = 8 waves; wave w owns q rows [qt*256+w*32, +32)
// Each lane owns ONE q column (lane&31): m/lsum lane-local. S^T = mfma(K, Q^T);
// O^T = mfma(V^T, P^T); P^T built in-register via pack + half-wave shfl swap.
__global__ __launch_bounds__(512, 4) void attn_kernel(const bf16* __restrict__ Q,
                                                      const bf16* __restrict__ Kb,
                                                      const bf16* __restrict__ Vt,
                                                      bf16* __restrict__ ctx) {
    __shared__ __align__(16) bf16 lds[4][4096];  // [0..1]=K dbuf, [2..3]=V^T dbuf (32 KiB)
    const int qt = 7 - (int)blockIdx.x;  // heavy blocks dispatch first
    const int bh = blockIdx.y;
    const int tid = threadIdx.x;
    const int lane = tid & 63, w = tid >> 6;
    const int lq = lane & 31, hi = lane >> 5;
    const int q0 = qt * 256;
    const int q0w = q0 + w * 32;
    const int q = q0w + lq;
    const int njt = 4 * qt + 4;
    const float qscale = 0.125f * 1.44269504088896340736f;  // 1/sqrt(DK)*log2(e)

    // staging: thread t covers 16B slot (t&7) of row (t>>3); source pre-swizzled
    const int srow = tid >> 3;
    const int sslot = (tid & 7) ^ (srow & 7);
    const bf16* kg = Kb + ((size_t)bh * S_ + srow) * DK_ + sslot * 8;
    const bf16* vg = Vt + ((size_t)bh * DK_ + srow) * S_ + sslot * 8;

    // Q fragments (pre-scaled): qf[kc][e] = Q[q][kc*16 + hi*8 + e] * qscale
    bf16x8 qf[4];
    {
        const bf16* qp = Q + ((size_t)bh * S_ + q) * DK_ + hi * 8;
#pragma unroll
        for (int kc = 0; kc < 4; ++kc) {
            bf16x8 raw = *(const bf16x8*)(qp + kc * 16);
#pragma unroll
            for (int e = 0; e < 8; ++e) qf[kc][e] = (bf16)((float)raw[e] * qscale);
        }
    }

    f32x16 accd[2] = {};  // O^T: d = dt*32 + (r&3)+8*(r>>2)+4*hi, col q = lq
    float m = -INFINITY, lsum = 0.f;

    bf16x8 kreg = *(const bf16x8*)kg;
    bf16x8 vreg = *(const bf16x8*)vg;

    for (int jt = 0; jt < njt; ++jt) {
        const int cur = jt & 1;
        *(bf16x8*)&lds[cur][tid * 8] = kreg;
        *(bf16x8*)&lds[2 + cur][tid * 8] = vreg;
        if (jt + 1 < njt) {
            kreg = *(const bf16x8*)(kg + (size_t)(jt + 1) * 64 * DK_);
            vreg = *(const bf16x8*)(vg + (jt + 1) * 64);
        }
        __syncthreads();

        if (jt * 64 <= q0w + 31) {  // wave has at least one unmasked key
            // ---- QK^T (S^T = K @ Q^T) ----
            f32x16 sacc[2] = {};
            __builtin_amdgcn_s_setprio(1);
#pragma unroll
            for (int kc = 0; kc < 4; ++kc) {
#pragma unroll
                for (int c = 0; c < 2; ++c) {
                    bf16x8 kf = *(const bf16x8*)&lds[cur][swz8(c * 32 + lq, kc * 2 + hi)];
                    sacc[c] = __builtin_amdgcn_mfma_f32_32x32x16_bf16(kf, qf[kc], sacc[c], 0, 0, 0);
                }
            }
            __builtin_amdgcn_s_setprio(0);

            // ---- causal mask (diagonal tiles only) ----
            if (jt * 64 + 63 > q0w) {
#pragma unroll
                for (int c = 0; c < 2; ++c)
#pragma unroll
                    for (int r = 0; r < 16; ++r) {
                        int key = jt * 64 + c * 32 + (r & 3) + 8 * (r >> 2) + 4 * hi;
                        if (key > q) sacc[c][r] = -INFINITY;
                    }
            }

            // ---- online softmax (lane-local per q column) ----
            float vm = sacc[0][0];
#pragma unroll
            for (int c = 0; c < 2; ++c)
#pragma unroll
                for (int r = 0; r < 16; ++r) vm = fmaxf(vm, sacc[c][r]);
            vm = fmaxf(vm, __shfl_xor(vm, 32));
            float mnew = fmaxf(m, vm);
            float alpha = exp2f(m - mnew);
            m = mnew;

            float psum = 0.f;
#pragma unroll
            for (int c = 0; c < 2; ++c)
#pragma unroll
                for (int r = 0; r < 16; ++r) {
                    float p = exp2f(sacc[c][r] - mnew);
                    sacc[c][r] = p;
                    psum += p;
                }
            psum += __shfl_xor(psum, 32);
            lsum = lsum * alpha + psum;
#pragma unroll
            for (int dt = 0; dt < 2; ++dt)
#pragma unroll
                for (int r = 0; r < 16; ++r) accd[dt][r] *= alpha;

            // ---- PV (O^T += V^T @ P^T), P^T frags in-register ----
#pragma unroll
            for (int kc = 0; kc < 4; ++kc) {
                const int c = kc >> 1, kf2 = kc & 1;
                unsigned A0 = packbf(sacc[c][8 * kf2 + 0], sacc[c][8 * kf2 + 1]);
                unsigned A1 = packbf(sacc[c][8 * kf2 + 2], sacc[c][8 * kf2 + 3]);
                unsigned B0 = packbf(sacc[c][8 * kf2 + 4], sacc[c][8 * kf2 + 5]);
                unsigned B1 = packbf(sacc[c][8 * kf2 + 6], sacc[c][8 * kf2 + 7]);
                unsigned sA0 = (unsigned)__shfl_xor((int)A0, 32);
                unsigned sA1 = (unsigned)__shfl_xor((int)A1, 32);
                unsigned sB0 = (unsigned)__shfl_xor((int)B0, 32);
                unsigned sB1 = (unsigned)__shfl_xor((int)B1, 32);
                union { unsigned wd[4]; bf16x8 v; } u;
                u.wd[0] = hi ? sB0 : A0;
                u.wd[1] = hi ? sB1 : A1;
                u.wd[2] = hi ? B0 : sA0;
                u.wd[3] = hi ? B1 : sA1;
                __builtin_amdgcn_s_setprio(1);
#pragma unroll
                for (int dt = 0; dt < 2; ++dt) {
                    bf16x8 vf = *(const bf16x8*)&lds[2 + cur][swz8(dt * 32 + lq, kc * 2 + hi)];
                    accd[dt] = __builtin_amdgcn_mfma_f32_32x32x16_bf16(vf, u.v, accd[dt], 0, 0, 0);
                }
                __builtin_amdgcn_s_setprio(0);
            }
        }
    }

    // ---- epilogue: O^T frags -> LDS (transpose) -> coalesced bf16 store ----
    __syncthreads();
    bf16* eb = &lds[0][0];  // 32 KiB = 256 rows x 128B
    const float rl = 1.0f / lsum;
    {
        const int rowb = (w * 32 + lq) * 128;
        const int rsw = (lq & 7) << 4;
#pragma unroll
        for (int dt = 0; dt < 2; ++dt)
#pragma unroll
            for (int rq = 0; rq < 4; ++rq) {
                union { bf16 h[4]; unsigned long long u64; } pk;
#pragma unroll
                for (int j = 0; j < 4; ++j) pk.h[j] = (bf16)(accd[dt][rq * 4 + j] * rl);
                int off = rowb + ((dt * 64 + rq * 16 + hi * 8) ^ rsw);
                *(unsigned long long*)((char*)eb + off) = pk.u64;
            }
    }
    __syncthreads();
    {
        const int row = tid >> 1, half = tid & 1;
        const int b = bh >> 4, h = bh & 15;
        bf16* op = ctx + ((size_t)b * S_ + q0 + row) * D_ + h * DK_ + half * 32;
#pragma unroll
        for (int i = 0; i < 4; ++i) {
            int sl = half * 4 + i;
            int sls = sl ^ (row & 7);
            bf16x8 v = *(const bf16x8*)((const char*)eb + row * 128 + sls * 16);
            *(bf16x8*)(op + i * 8) = v;
        }
    }
}

extern "C" void kernel_launch(void* const* d_in, const int* in_sizes, int n_in,
                              void* d_out, int out_size, void* d_ws, size_t ws_size,
                              hipStream_t stream) {
    const float* x  = (const float*)d_in[0];
    const float* wq = (const float*)d_in[1];
    const float* wk = (const float*)d_in[2];
    const float* wv = (const float*)d_in[3];
    const float* wo = (const float*)d_in[4];

    char* ws = (char*)d_ws;
    bf16* wqkvT = (bf16*)(ws);                    // 6291456 B
    bf16* woT   = (bf16*)(ws + 6291456);          // 2097152 B
    bf16* Qb    = (bf16*)(ws + 8388608);          // 16777216 B
    bf16* Kb    = (bf16*)(ws + 25165824);         // 16777216 B
    bf16* Vb    = (bf16*)(ws + 41943040);         // 16777216 B
    bf16* Vtb   = (bf16*)(ws + 58720256);         // 16777216 B
    bf16* ctx   = (bf16*)(ws + 75497472);         // 16777216 B

    transpose_w_kernel<<<dim3(32, 32, 4), dim3(32, 8), 0, stream>>>(wq, wk, wv, wo, wqkvT, woT);
    gemm_kernel<0><<<dim3(24, 64), 256, 0, stream>>>(x, wqkvT, Qb, Kb, Vb, 8192, 3072, 1024);
    transpose_v_kernel<<<dim3(32, 64), 256, 0, stream>>>(Vb, Vtb);
    attn_kernel<<<dim3(8, 64), 512, 0, stream>>>(Qb, Kb, Vtb, ctx);
    gemm_kernel<1><<<dim3(8, 64), 256, 0, stream>>>(ctx, woT, d_out, nullptr, nullptr, 8192, 1024, 1024);
}

// Round 3
// 205.860 us; speedup vs baseline: 1.7274x; 1.2145x over previous
//
#include <hip/hip_runtime.h>
#include <hip/hip_bf16.h>
#include <math.h>

#define B_ 4
#define S_ 2048
#define D_ 1024
#define H_ 16
#define DK_ 64

typedef __bf16 bf16;
typedef bf16 bf16x8 __attribute__((ext_vector_type(8)));
typedef float f32x4 __attribute__((ext_vector_type(4)));
typedef float f32x16 __attribute__((ext_vector_type(16)));

// XOR swizzle for [rows][64-bf16] LDS tiles (128B rows, 8x16B slots)
__device__ __forceinline__ int swz8(int row, int slot) {
    return row * 64 + ((slot ^ (row & 7)) << 3);
}
__device__ __forceinline__ unsigned packbf(float a, float b) {
    union { bf16 h[2]; unsigned u; } x;
    x.h[0] = (bf16)a; x.h[1] = (bf16)b;
    return x.u;
}
// v_permlane32_swap_b32: x' = [x.lo, y.lo], y' = [x.hi, y.hi] (32-lane halves)
__device__ __forceinline__ void permswap(unsigned& x, unsigned& y) {
    asm("v_permlane32_swap_b32 %0, %1" : "+v"(x), "+v"(y));
}

// ---------------- weight transpose + cast: dst[n][k] = (bf16) src[k][n] ----------------
__global__ void transpose_w_kernel(const float* wq, const float* wk, const float* wv, const float* wo,
                                   bf16* wqkvT, bf16* woT) {
    __shared__ float t[32][33];
    const int z = blockIdx.z;
    const float* src = (z == 0) ? wq : (z == 1) ? wk : (z == 2) ? wv : wo;
    bf16* dst = (z < 3) ? (wqkvT + (size_t)z * 1024 * 1024) : woT;
    const int n0 = blockIdx.x * 32, k0 = blockIdx.y * 32;
    const int tx = threadIdx.x, ty = threadIdx.y;
#pragma unroll
    for (int j = 0; j < 4; ++j)
        t[ty + j * 8][tx] = src[(size_t)(k0 + ty + j * 8) * 1024 + n0 + tx];
    __syncthreads();
#pragma unroll
    for (int j = 0; j < 4; ++j)
        dst[(size_t)(n0 + ty + j * 8) * 1024 + k0 + tx] = (bf16)t[tx][ty + j * 8];
}

// ---------------- GEMM: C[M,N] = A[M,K] @ Bt[N,K]^T, bf16 MFMA, fp32 accum ----------------
template <int MODE>
__global__ __launch_bounds__(256) void gemm_kernel(const void* Av, const bf16* Bt,
                                                   void* o0, void* o1, void* o2,
                                                   int M, int N, int K) {
    __shared__ __align__(16) bf16 As[128 * 64];
    __shared__ __align__(16) bf16 Bs[128 * 64];
    const int tid = threadIdx.x;
    const int lane = tid & 63;
    const int w = tid >> 6;
    const int wm = w >> 1, wn = w & 1;
    const int g = lane >> 4, r16 = lane & 15;
    const int m0 = blockIdx.y * 128, n0 = blockIdx.x * 128;
    const int rS = tid >> 3, cS = tid & 7;

    f32x4 acc[4][4] = {};

    for (int kt = 0; kt < K; kt += 64) {
        if (MODE == 0) {
            const float* A = (const float*)Av;
#pragma unroll
            for (int p = 0; p < 4; ++p) {
                int r = p * 32 + rS;
                const float4* src = (const float4*)(A + (size_t)(m0 + r) * K + kt + cS * 8);
                float4 f0 = src[0], f1 = src[1];
                bf16x8 v;
                v[0] = (bf16)f0.x; v[1] = (bf16)f0.y; v[2] = (bf16)f0.z; v[3] = (bf16)f0.w;
                v[4] = (bf16)f1.x; v[5] = (bf16)f1.y; v[6] = (bf16)f1.z; v[7] = (bf16)f1.w;
                *(bf16x8*)&As[swz8(r, cS)] = v;
            }
        } else {
            const bf16* A = (const bf16*)Av;
#pragma unroll
            for (int p = 0; p < 4; ++p) {
                int r = p * 32 + rS;
                *(bf16x8*)&As[swz8(r, cS)] = *(const bf16x8*)(A + (size_t)(m0 + r) * K + kt + cS * 8);
            }
        }
#pragma unroll
        for (int p = 0; p < 4; ++p) {
            int r = p * 32 + rS;
            *(bf16x8*)&Bs[swz8(r, cS)] = *(const bf16x8*)(Bt + (size_t)(n0 + r) * K + kt + cS * 8);
        }
        __syncthreads();
#pragma unroll
        for (int k0 = 0; k0 < 2; ++k0) {
            bf16x8 af[4], bfr[4];
#pragma unroll
            for (int mf = 0; mf < 4; ++mf)
                af[mf] = *(const bf16x8*)&As[swz8(wm * 64 + mf * 16 + r16, 4 * k0 + g)];
#pragma unroll
            for (int nf = 0; nf < 4; ++nf)
                bfr[nf] = *(const bf16x8*)&Bs[swz8(wn * 64 + nf * 16 + r16, 4 * k0 + g)];
#pragma unroll
            for (int mf = 0; mf < 4; ++mf)
#pragma unroll
                for (int nf = 0; nf < 4; ++nf)
                    acc[mf][nf] = __builtin_amdgcn_mfma_f32_16x16x32_bf16(af[mf], bfr[nf], acc[mf][nf], 0, 0, 0);
        }
        __syncthreads();
    }

#pragma unroll
    for (int mf = 0; mf < 4; ++mf) {
#pragma unroll
        for (int nf = 0; nf < 4; ++nf) {
#pragma unroll
            for (int rr = 0; rr < 4; ++rr) {
                int row = m0 + wm * 64 + mf * 16 + 4 * g + rr;
                int col = n0 + wn * 64 + nf * 16 + r16;
                float val = acc[mf][nf][rr];
                if (MODE == 0) {
                    int seg = col >> 10, n1 = col & 1023;
                    int h = n1 >> 6, dk = n1 & 63;
                    int b = row >> 11, s = row & 2047;
                    size_t idx = (((size_t)b * H_ + h) * S_ + s) * DK_ + dk;
                    bf16 bv = (bf16)val;
                    if (seg == 0) ((bf16*)o0)[idx] = bv;
                    else if (seg == 1) ((bf16*)o1)[idx] = bv;
                    else ((bf16*)o2)[idx] = bv;
                } else {
                    ((float*)o0)[(size_t)row * N + col] = val;
                }
            }
        }
    }
}

// ---------------- V [b,h,s,dk] -> Vt [b,h,dk,s] ----------------
__global__ __launch_bounds__(256) void transpose_v_kernel(const bf16* V, bf16* Vt) {
    __shared__ __align__(16) bf16 t[64][68];
    const int st = blockIdx.x, bh = blockIdx.y;
    const int tid = threadIdx.x;
#pragma unroll
    for (int p = 0; p < 2; ++p) {
        int chunk = tid + p * 256;
        int sl = chunk >> 3, c = chunk & 7;
        bf16x8 v = *(const bf16x8*)(V + ((size_t)bh * S_ + st * 64 + sl) * DK_ + c * 8);
#pragma unroll
        for (int e = 0; e < 8; ++e) t[c * 8 + e][sl] = v[e];
    }
    __syncthreads();
#pragma unroll
    for (int p = 0; p < 4; ++p) {
        int chunk = tid + p * 256;
        int dk = chunk >> 4, sc = chunk & 15;
        ushort4 v = *(const ushort4*)&t[dk][sc * 4];
        *(ushort4*)(Vt + ((size_t)bh * DK_ + dk) * S_ + st * 64 + sc * 4) = v;
    }
}

// ---------------- causal flash attention, swapped-operand 32x32x16 ----------------
// grid (64 bh, 16 qtiles); block 256 = 4 waves; wave w owns q rows [qt*128+w*32, +32)
// Lane owns ONE q column (lane&31). S^T = mfma(K, Q^T); O^T = mfma(V^T, P^T);
// P^T built in-register: cvt-pack pairs + v_permlane32_swap (no LDS round trip).
__global__ __launch_bounds__(256, 4) void attn_kernel(const bf16* __restrict__ Q,
                                                      const bf16* __restrict__ Kb,
                                                      const bf16* __restrict__ Vt,
                                                      bf16* __restrict__ ctx) {
    __shared__ __align__(16) bf16 lds[4][4096];  // [0..1]=K dbuf, [2..3]=V^T dbuf (32 KiB)
    const int bh = blockIdx.x;                   // bh on x: all blocks of a bh share an XCD
    const int qt = 15 - (int)blockIdx.y;         // heavy q-tiles dispatch first
    const int tid = threadIdx.x;
    const int lane = tid & 63, w = tid >> 6;
    const int lq = lane & 31, hi = lane >> 5;
    const int q0 = qt * 128;
    const int q0w = q0 + w * 32;
    const int q = q0w + lq;
    const int njt = 2 * qt + 2;
    const float qscale = 0.125f * 1.44269504088896340736f;  // 1/sqrt(DK)*log2(e)

    // staging: 256 threads cover 64 rows x 8 slots in two halves; source pre-swizzled
    const int srow = tid >> 3;
    const int sslot = (tid & 7) ^ (srow & 7);
    const bf16* kg = Kb + ((size_t)bh * S_ + srow) * DK_ + sslot * 8;
    const bf16* vg = Vt + ((size_t)bh * DK_ + srow) * S_ + sslot * 8;

    // Q fragments (pre-scaled): qf[kc][e] = Q[q][kc*16 + hi*8 + e] * qscale
    bf16x8 qf[4];
    {
        const bf16* qp = Q + ((size_t)bh * S_ + q) * DK_ + hi * 8;
#pragma unroll
        for (int kc = 0; kc < 4; ++kc) {
            bf16x8 raw = *(const bf16x8*)(qp + kc * 16);
#pragma unroll
            for (int e = 0; e < 8; ++e) qf[kc][e] = (bf16)((float)raw[e] * qscale);
        }
    }

    f32x16 accd[2] = {};  // O^T: dk = dt*32 + (r&3)+8*(r>>2)+4*hi, col q = lq
    float m = -INFINITY, lsum = 0.f;

    bf16x8 kreg0 = *(const bf16x8*)kg;
    bf16x8 kreg1 = *(const bf16x8*)(kg + 32 * DK_);
    bf16x8 vreg0 = *(const bf16x8*)vg;
    bf16x8 vreg1 = *(const bf16x8*)(vg + 32 * S_);

    for (int jt = 0; jt < njt; ++jt) {
        const int cur = jt & 1;
        *(bf16x8*)&lds[cur][tid * 8] = kreg0;
        *(bf16x8*)&lds[cur][tid * 8 + 2048] = kreg1;
        *(bf16x8*)&lds[2 + cur][tid * 8] = vreg0;
        *(bf16x8*)&lds[2 + cur][tid * 8 + 2048] = vreg1;
        if (jt + 1 < njt) {
            kreg0 = *(const bf16x8*)(kg + (size_t)(jt + 1) * 64 * DK_);
            kreg1 = *(const bf16x8*)(kg + (size_t)(jt + 1) * 64 * DK_ + 32 * DK_);
            vreg0 = *(const bf16x8*)(vg + (jt + 1) * 64);
            vreg1 = *(const bf16x8*)(vg + (jt + 1) * 64 + 32 * S_);
        }
        __syncthreads();

        if (jt * 64 <= q0w + 31) {  // wave has at least one unmasked key
            // ---- QK^T (S^T = K @ Q^T) ----
            f32x16 sacc[2] = {};
            __builtin_amdgcn_s_setprio(1);
#pragma unroll
            for (int kc = 0; kc < 4; ++kc) {
#pragma unroll
                for (int c = 0; c < 2; ++c) {
                    bf16x8 kf = *(const bf16x8*)&lds[cur][swz8(c * 32 + lq, kc * 2 + hi)];
                    sacc[c] = __builtin_amdgcn_mfma_f32_32x32x16_bf16(kf, qf[kc], sacc[c], 0, 0, 0);
                }
            }
            __builtin_amdgcn_s_setprio(0);

            // ---- causal mask (diagonal tiles only) ----
            if (jt * 64 + 63 > q0w) {
#pragma unroll
                for (int c = 0; c < 2; ++c)
#pragma unroll
                    for (int r = 0; r < 16; ++r) {
                        int key = jt * 64 + c * 32 + (r & 3) + 8 * (r >> 2) + 4 * hi;
                        if (key > q) sacc[c][r] = -INFINITY;
                    }
            }

            // ---- per-tile max: tree reduce (depth 5) ----
            float tm[16];
#pragma unroll
            for (int i = 0; i < 16; ++i) tm[i] = fmaxf(sacc[0][i], sacc[1][i]);
#pragma unroll
            for (int s = 8; s >= 1; s >>= 1)
#pragma unroll
                for (int i = 0; i < s; ++i) tm[i] = fmaxf(tm[i], tm[i + s]);
            float pmax = fmaxf(tm[0], __shfl_xor(tm[0], 32));

            // ---- defer-max (T13): rescale only when max grew past THR ----
            if (!__all(pmax - m <= 8.0f)) {
                float mnew = fmaxf(m, pmax);
                float alpha = exp2f(m - mnew);
                m = mnew;
                lsum *= alpha;
#pragma unroll
                for (int dt = 0; dt < 2; ++dt)
#pragma unroll
                    for (int r = 0; r < 16; ++r) accd[dt][r] *= alpha;
            }

            // ---- P = exp2(S - m), sum via tree ----
#pragma unroll
            for (int c = 0; c < 2; ++c)
#pragma unroll
                for (int r = 0; r < 16; ++r) sacc[c][r] = exp2f(sacc[c][r] - m);
            float ts[16];
#pragma unroll
            for (int i = 0; i < 16; ++i) ts[i] = sacc[0][i] + sacc[1][i];
#pragma unroll
            for (int s = 8; s >= 1; s >>= 1)
#pragma unroll
                for (int i = 0; i < s; ++i) ts[i] += ts[i + s];
            lsum += ts[0] + __shfl_xor(ts[0], 32);

            // ---- PV (O^T += V^T @ P^T), P^T frags via pack + permlane32_swap ----
#pragma unroll
            for (int kc = 0; kc < 4; ++kc) {
                const int c = kc >> 1, kf2 = kc & 1;
                unsigned w0 = packbf(sacc[c][8 * kf2 + 0], sacc[c][8 * kf2 + 1]);
                unsigned w1 = packbf(sacc[c][8 * kf2 + 2], sacc[c][8 * kf2 + 3]);
                unsigned w2 = packbf(sacc[c][8 * kf2 + 4], sacc[c][8 * kf2 + 5]);
                unsigned w3 = packbf(sacc[c][8 * kf2 + 6], sacc[c][8 * kf2 + 7]);
                permswap(w0, w2);  // w0=[w0.lo,w2.lo]  w2=[w0.hi,w2.hi]
                permswap(w1, w3);
                union { unsigned wd[4]; bf16x8 v; } u;
                u.wd[0] = w0; u.wd[1] = w1; u.wd[2] = w2; u.wd[3] = w3;
                __builtin_amdgcn_s_setprio(1);
#pragma unroll
                for (int dt = 0; dt < 2; ++dt) {
                    bf16x8 vf = *(const bf16x8*)&lds[2 + cur][swz8(dt * 32 + lq, kc * 2 + hi)];
                    accd[dt] = __builtin_amdgcn_mfma_f32_32x32x16_bf16(vf, u.v, accd[dt], 0, 0, 0);
                }
                __builtin_amdgcn_s_setprio(0);
            }
        }
    }

    // ---- epilogue: O^T frags -> LDS (transpose) -> coalesced bf16 store ----
    __syncthreads();
    bf16* eb = &lds[0][0];  // 16 KiB: 128 rows x 128B
    const float rl = 1.0f / lsum;
    {
        const int rowb = (w * 32 + lq) * 128;
        const int rsw = (lq & 7) << 4;
#pragma unroll
        for (int dt = 0; dt < 2; ++dt)
#pragma unroll
            for (int rq = 0; rq < 4; ++rq) {
                union { bf16 h[4]; unsigned long long u64; } pk;
#pragma unroll
                for (int j = 0; j < 4; ++j) pk.h[j] = (bf16)(accd[dt][rq * 4 + j] * rl);
                int off = rowb + ((dt * 64 + rq * 16 + hi * 8) ^ rsw);
                *(unsigned long long*)((char*)eb + off) = pk.u64;
            }
    }
    __syncthreads();
    {
        const int row = tid >> 1, half = tid & 1;
        const int b = bh >> 4, h = bh & 15;
        bf16* op = ctx + ((size_t)b * S_ + q0 + row) * D_ + h * DK_ + half * 32;
#pragma unroll
        for (int i = 0; i < 4; ++i) {
            int sl = half * 4 + i;
            int sls = sl ^ (row & 7);
            bf16x8 v = *(const bf16x8*)((const char*)eb + row * 128 + sls * 16);
            *(bf16x8*)(op + i * 8) = v;
        }
    }
}

extern "C" void kernel_launch(void* const* d_in, const int* in_sizes, int n_in,
                              void* d_out, int out_size, void* d_ws, size_t ws_size,
                              hipStream_t stream) {
    const float* x  = (const float*)d_in[0];
    const float* wq = (const float*)d_in[1];
    const float* wk = (const float*)d_in[2];
    const float* wv = (const float*)d_in[3];
    const float* wo = (const float*)d_in[4];

    char* ws = (char*)d_ws;
    bf16* wqkvT = (bf16*)(ws);                    // 6291456 B
    bf16* woT   = (bf16*)(ws + 6291456);          // 2097152 B
    bf16* Qb    = (bf16*)(ws + 8388608);          // 16777216 B
    bf16* Kb    = (bf16*)(ws + 25165824);         // 16777216 B
    bf16* Vb    = (bf16*)(ws + 41943040);         // 16777216 B
    bf16* Vtb   = (bf16*)(ws + 58720256);         // 16777216 B
    bf16* ctx   = (bf16*)(ws + 75497472);         // 16777216 B

    transpose_w_kernel<<<dim3(32, 32, 4), dim3(32, 8), 0, stream>>>(wq, wk, wv, wo, wqkvT, woT);
    gemm_kernel<0><<<dim3(24, 64), 256, 0, stream>>>(x, wqkvT, Qb, Kb, Vb, 8192, 3072, 1024);
    transpose_v_kernel<<<dim3(32, 64), 256, 0, stream>>>(Vb, Vtb);
    attn_kernel<<<dim3(64, 16), 256, 0, stream>>>(Qb, Kb, Vtb, ctx);
    gemm_kernel<1><<<dim3(8, 64), 256, 0, stream>>>(ctx, woT, d_out, nullptr, nullptr, 8192, 1024, 1024);
}

// Round 4
// 191.374 us; speedup vs baseline: 1.8582x; 1.0757x over previous
//
#include <hip/hip_runtime.h>
#include <hip/hip_bf16.h>
#include <math.h>

#define B_ 4
#define S_ 2048
#define D_ 1024
#define H_ 16
#define DK_ 64

typedef __bf16 bf16;
typedef bf16 bf16x8 __attribute__((ext_vector_type(8)));
typedef float f32x4 __attribute__((ext_vector_type(4)));
typedef float f32x16 __attribute__((ext_vector_type(16)));

// XOR swizzle for [rows][64-bf16] LDS tiles (128B rows, 8x16B slots)
__device__ __forceinline__ int swz8(int row, int slot) {
    return row * 64 + ((slot ^ (row & 7)) << 3);
}
__device__ __forceinline__ unsigned packbf(float a, float b) {
    union { bf16 h[2]; unsigned u; } x;
    x.h[0] = (bf16)a; x.h[1] = (bf16)b;
    return x.u;
}
// v_permlane32_swap_b32: x' = [x.lo, y.lo], y' = [x.hi, y.hi] (32-lane halves)
__device__ __forceinline__ void permswap(unsigned& x, unsigned& y) {
    asm("v_permlane32_swap_b32 %0, %1" : "+v"(x), "+v"(y));
}
// async global->LDS, 16B per lane; lbase must be wave-uniform, gsrc per-lane
__device__ __forceinline__ void gld16(bf16* lbase, const bf16* gsrc) {
    __builtin_amdgcn_global_load_lds(
        (const __attribute__((address_space(1))) unsigned*)gsrc,
        (__attribute__((address_space(3))) unsigned*)lbase, 16, 0, 0);
}

// ---------------- x fp32 -> bf16 ----------------
__global__ __launch_bounds__(256) void cast_x_kernel(const float* __restrict__ x, bf16* __restrict__ xb) {
    const size_t i = ((size_t)blockIdx.x * 256 + threadIdx.x) * 8;
    const float4* src = (const float4*)(x + i);
    float4 f0 = src[0], f1 = src[1];
    bf16x8 v;
    v[0] = (bf16)f0.x; v[1] = (bf16)f0.y; v[2] = (bf16)f0.z; v[3] = (bf16)f0.w;
    v[4] = (bf16)f1.x; v[5] = (bf16)f1.y; v[6] = (bf16)f1.z; v[7] = (bf16)f1.w;
    *(bf16x8*)(xb + i) = v;
}

// ---------------- weight transpose + cast: dst[n][k] = (bf16) src[k][n] ----------------
__global__ void transpose_w_kernel(const float* wq, const float* wk, const float* wv, const float* wo,
                                   bf16* wqkvT, bf16* woT) {
    __shared__ float t[32][33];
    const int z = blockIdx.z;
    const float* src = (z == 0) ? wq : (z == 1) ? wk : (z == 2) ? wv : wo;
    bf16* dst = (z < 3) ? (wqkvT + (size_t)z * 1024 * 1024) : woT;
    const int n0 = blockIdx.x * 32, k0 = blockIdx.y * 32;
    const int tx = threadIdx.x, ty = threadIdx.y;
#pragma unroll
    for (int j = 0; j < 4; ++j)
        t[ty + j * 8][tx] = src[(size_t)(k0 + ty + j * 8) * 1024 + n0 + tx];
    __syncthreads();
#pragma unroll
    for (int j = 0; j < 4; ++j)
        dst[(size_t)(n0 + ty + j * 8) * 1024 + k0 + tx] = (bf16)t[tx][ty + j * 8];
}

// ---------------- GEMM: C[M,N] = A[M,K] @ Bt[N,K]^T, bf16 MFMA, fp32 accum ----------------
// m97 structure: global_load_lds staging (pre-swizzled source, linear LDS dest,
// swizzled read), 128x128 tile, BK=64, 4 waves. 1D grid, bijective XCD swizzle.
// MODE 0: epilogue scatters bf16 into Q/K/V [b,h,s,dk] (N=3072 concat)
// MODE 1: epilogue writes fp32 C to o0
template <int MODE>
__global__ __launch_bounds__(256) void gemm_kernel(const bf16* __restrict__ A, const bf16* __restrict__ Bt,
                                                   void* o0, void* o1, void* o2,
                                                   int M, int N, int K, int NT) {
    __shared__ __align__(16) bf16 As[128 * 64];
    __shared__ __align__(16) bf16 Bs[128 * 64];
    const int tid = threadIdx.x;
    const int lane = tid & 63;
    const int w = tid >> 6;
    const int wm = w >> 1, wn = w & 1;
    const int g = lane >> 4, r16 = lane & 15;

    // bijective XCD swizzle (gridDim.x % 8 == 0)
    const int bid = blockIdx.x;
    const int qch = gridDim.x >> 3;
    const int wg = (bid & 7) * qch + (bid >> 3);
    const int mt = wg / NT, nt = wg % NT;
    const int m0 = mt * 128, n0 = nt * 128;

    // staging: chunk c = p*256+tid covers LDS 16B slot (c&7) of row (c>>3);
    // global source slot pre-swizzled by the same XOR involution
    const int srow = tid >> 3;                 // row within 32-row stripe
    const int sslot = (tid & 7) ^ (srow & 7);  // 32 = 0 mod 8 -> same for all p
    const bf16* ga = A + (size_t)(m0 + srow) * K + sslot * 8;
    const bf16* gb = Bt + (size_t)(n0 + srow) * K + sslot * 8;

    f32x4 acc[4][4] = {};

    for (int kt = 0; kt < K; kt += 64) {
#pragma unroll
        for (int p = 0; p < 4; ++p) {
            gld16(&As[p * 2048 + w * 512], ga + (size_t)p * 32 * K + kt);
            gld16(&Bs[p * 2048 + w * 512], gb + (size_t)p * 32 * K + kt);
        }
        __syncthreads();
#pragma unroll
        for (int k0 = 0; k0 < 2; ++k0) {
            bf16x8 af[4], bfr[4];
#pragma unroll
            for (int mf = 0; mf < 4; ++mf)
                af[mf] = *(const bf16x8*)&As[swz8(wm * 64 + mf * 16 + r16, 4 * k0 + g)];
#pragma unroll
            for (int nf = 0; nf < 4; ++nf)
                bfr[nf] = *(const bf16x8*)&Bs[swz8(wn * 64 + nf * 16 + r16, 4 * k0 + g)];
#pragma unroll
            for (int mf = 0; mf < 4; ++mf)
#pragma unroll
                for (int nf = 0; nf < 4; ++nf)
                    acc[mf][nf] = __builtin_amdgcn_mfma_f32_16x16x32_bf16(af[mf], bfr[nf], acc[mf][nf], 0, 0, 0);
        }
        __syncthreads();
    }

#pragma unroll
    for (int mf = 0; mf < 4; ++mf) {
#pragma unroll
        for (int nf = 0; nf < 4; ++nf) {
#pragma unroll
            for (int rr = 0; rr < 4; ++rr) {
                int row = m0 + wm * 64 + mf * 16 + 4 * g + rr;
                int col = n0 + wn * 64 + nf * 16 + r16;
                float val = acc[mf][nf][rr];
                if (MODE == 0) {
                    int seg = col >> 10, n1 = col & 1023;
                    int h = n1 >> 6, dk = n1 & 63;
                    int b = row >> 11, s = row & 2047;
                    size_t idx = (((size_t)b * H_ + h) * S_ + s) * DK_ + dk;
                    bf16 bv = (bf16)val;
                    if (seg == 0) ((bf16*)o0)[idx] = bv;
                    else if (seg == 1) ((bf16*)o1)[idx] = bv;
                    else ((bf16*)o2)[idx] = bv;
                } else {
                    ((float*)o0)[(size_t)row * N + col] = val;
                }
            }
        }
    }
}

// ---------------- V [b,h,s,dk] -> Vt [b,h,dk,s] ----------------
__global__ __launch_bounds__(256) void transpose_v_kernel(const bf16* V, bf16* Vt) {
    __shared__ __align__(16) bf16 t[64][68];
    const int st = blockIdx.x, bh = blockIdx.y;
    const int tid = threadIdx.x;
#pragma unroll
    for (int p = 0; p < 2; ++p) {
        int chunk = tid + p * 256;
        int sl = chunk >> 3, c = chunk & 7;
        bf16x8 v = *(const bf16x8*)(V + ((size_t)bh * S_ + st * 64 + sl) * DK_ + c * 8);
#pragma unroll
        for (int e = 0; e < 8; ++e) t[c * 8 + e][sl] = v[e];
    }
    __syncthreads();
#pragma unroll
    for (int p = 0; p < 4; ++p) {
        int chunk = tid + p * 256;
        int dk = chunk >> 4, sc = chunk & 15;
        ushort4 v = *(const ushort4*)&t[dk][sc * 4];
        *(ushort4*)(Vt + ((size_t)bh * DK_ + dk) * S_ + st * 64 + sc * 4) = v;
    }
}

// ---------------- causal flash attention, swapped-operand 32x32x16 ----------------
__global__ __launch_bounds__(256, 4) void attn_kernel(const bf16* __restrict__ Q,
                                                      const bf16* __restrict__ Kb,
                                                      const bf16* __restrict__ Vt,
                                                      bf16* __restrict__ ctx) {
    __shared__ __align__(16) bf16 lds[4][4096];  // [0..1]=K dbuf, [2..3]=V^T dbuf (32 KiB)
    const int bh = blockIdx.x;                   // bh on x: all blocks of a bh share an XCD
    const int qt = 15 - (int)blockIdx.y;         // heavy q-tiles dispatch first
    const int tid = threadIdx.x;
    const int lane = tid & 63, w = tid >> 6;
    const int lq = lane & 31, hi = lane >> 5;
    const int q0 = qt * 128;
    const int q0w = q0 + w * 32;
    const int q = q0w + lq;
    const int njt = 2 * qt + 2;
    const float qscale = 0.125f * 1.44269504088896340736f;  // 1/sqrt(DK)*log2(e)

    const int srow = tid >> 3;
    const int sslot = (tid & 7) ^ (srow & 7);
    const bf16* kg = Kb + ((size_t)bh * S_ + srow) * DK_ + sslot * 8;
    const bf16* vg = Vt + ((size_t)bh * DK_ + srow) * S_ + sslot * 8;

    bf16x8 qf[4];
    {
        const bf16* qp = Q + ((size_t)bh * S_ + q) * DK_ + hi * 8;
#pragma unroll
        for (int kc = 0; kc < 4; ++kc) {
            bf16x8 raw = *(const bf16x8*)(qp + kc * 16);
#pragma unroll
            for (int e = 0; e < 8; ++e) qf[kc][e] = (bf16)((float)raw[e] * qscale);
        }
    }

    f32x16 accd[2] = {};  // O^T: dk = dt*32 + (r&3)+8*(r>>2)+4*hi, col q = lq
    float m = -INFINITY, lsum = 0.f;

    bf16x8 kreg0 = *(const bf16x8*)kg;
    bf16x8 kreg1 = *(const bf16x8*)(kg + 32 * DK_);
    bf16x8 vreg0 = *(const bf16x8*)vg;
    bf16x8 vreg1 = *(const bf16x8*)(vg + 32 * S_);

    for (int jt = 0; jt < njt; ++jt) {
        const int cur = jt & 1;
        *(bf16x8*)&lds[cur][tid * 8] = kreg0;
        *(bf16x8*)&lds[cur][tid * 8 + 2048] = kreg1;
        *(bf16x8*)&lds[2 + cur][tid * 8] = vreg0;
        *(bf16x8*)&lds[2 + cur][tid * 8 + 2048] = vreg1;
        if (jt + 1 < njt) {
            kreg0 = *(const bf16x8*)(kg + (size_t)(jt + 1) * 64 * DK_);
            kreg1 = *(const bf16x8*)(kg + (size_t)(jt + 1) * 64 * DK_ + 32 * DK_);
            vreg0 = *(const bf16x8*)(vg + (jt + 1) * 64);
            vreg1 = *(const bf16x8*)(vg + (jt + 1) * 64 + 32 * S_);
        }
        __syncthreads();

        if (jt * 64 <= q0w + 31) {
            // ---- QK^T (S^T = K @ Q^T) ----
            f32x16 sacc[2] = {};
            __builtin_amdgcn_s_setprio(1);
#pragma unroll
            for (int kc = 0; kc < 4; ++kc) {
#pragma unroll
                for (int c = 0; c < 2; ++c) {
                    bf16x8 kf = *(const bf16x8*)&lds[cur][swz8(c * 32 + lq, kc * 2 + hi)];
                    sacc[c] = __builtin_amdgcn_mfma_f32_32x32x16_bf16(kf, qf[kc], sacc[c], 0, 0, 0);
                }
            }
            __builtin_amdgcn_s_setprio(0);

            if (jt * 64 + 63 > q0w) {
#pragma unroll
                for (int c = 0; c < 2; ++c)
#pragma unroll
                    for (int r = 0; r < 16; ++r) {
                        int key = jt * 64 + c * 32 + (r & 3) + 8 * (r >> 2) + 4 * hi;
                        if (key > q) sacc[c][r] = -INFINITY;
                    }
            }

            float tm[16];
#pragma unroll
            for (int i = 0; i < 16; ++i) tm[i] = fmaxf(sacc[0][i], sacc[1][i]);
#pragma unroll
            for (int s = 8; s >= 1; s >>= 1)
#pragma unroll
                for (int i = 0; i < s; ++i) tm[i] = fmaxf(tm[i], tm[i + s]);
            float pmax = fmaxf(tm[0], __shfl_xor(tm[0], 32));

            if (!__all(pmax - m <= 8.0f)) {
                float mnew = fmaxf(m, pmax);
                float alpha = exp2f(m - mnew);
                m = mnew;
                lsum *= alpha;
#pragma unroll
                for (int dt = 0; dt < 2; ++dt)
#pragma unroll
                    for (int r = 0; r < 16; ++r) accd[dt][r] *= alpha;
            }

#pragma unroll
            for (int c = 0; c < 2; ++c)
#pragma unroll
                for (int r = 0; r < 16; ++r) sacc[c][r] = exp2f(sacc[c][r] - m);
            float ts[16];
#pragma unroll
            for (int i = 0; i < 16; ++i) ts[i] = sacc[0][i] + sacc[1][i];
#pragma unroll
            for (int s = 8; s >= 1; s >>= 1)
#pragma unroll
                for (int i = 0; i < s; ++i) ts[i] += ts[i + s];
            lsum += ts[0] + __shfl_xor(ts[0], 32);

#pragma unroll
            for (int kc = 0; kc < 4; ++kc) {
                const int c = kc >> 1, kf2 = kc & 1;
                unsigned w0 = packbf(sacc[c][8 * kf2 + 0], sacc[c][8 * kf2 + 1]);
                unsigned w1 = packbf(sacc[c][8 * kf2 + 2], sacc[c][8 * kf2 + 3]);
                unsigned w2 = packbf(sacc[c][8 * kf2 + 4], sacc[c][8 * kf2 + 5]);
                unsigned w3 = packbf(sacc[c][8 * kf2 + 6], sacc[c][8 * kf2 + 7]);
                permswap(w0, w2);
                permswap(w1, w3);
                union { unsigned wd[4]; bf16x8 v; } u;
                u.wd[0] = w0; u.wd[1] = w1; u.wd[2] = w2; u.wd[3] = w3;
                __builtin_amdgcn_s_setprio(1);
#pragma unroll
                for (int dt = 0; dt < 2; ++dt) {
                    bf16x8 vf = *(const bf16x8*)&lds[2 + cur][swz8(dt * 32 + lq, kc * 2 + hi)];
                    accd[dt] = __builtin_amdgcn_mfma_f32_32x32x16_bf16(vf, u.v, accd[dt], 0, 0, 0);
                }
                __builtin_amdgcn_s_setprio(0);
            }
        }
    }

    __syncthreads();
    bf16* eb = &lds[0][0];
    const float rl = 1.0f / lsum;
    {
        const int rowb = (w * 32 + lq) * 128;
        const int rsw = (lq & 7) << 4;
#pragma unroll
        for (int dt = 0; dt < 2; ++dt)
#pragma unroll
            for (int rq = 0; rq < 4; ++rq) {
                union { bf16 h[4]; unsigned long long u64; } pk;
#pragma unroll
                for (int j = 0; j < 4; ++j) pk.h[j] = (bf16)(accd[dt][rq * 4 + j] * rl);
                int off = rowb + ((dt * 64 + rq * 16 + hi * 8) ^ rsw);
                *(unsigned long long*)((char*)eb + off) = pk.u64;
            }
    }
    __syncthreads();
    {
        const int row = tid >> 1, half = tid & 1;
        const int b = bh >> 4, h = bh & 15;
        bf16* op = ctx + ((size_t)b * S_ + q0 + row) * D_ + h * DK_ + half * 32;
#pragma unroll
        for (int i = 0; i < 4; ++i) {
            int sl = half * 4 + i;
            int sls = sl ^ (row & 7);
            bf16x8 v = *(const bf16x8*)((const char*)eb + row * 128 + sls * 16);
            *(bf16x8*)(op + i * 8) = v;
        }
    }
}

extern "C" void kernel_launch(void* const* d_in, const int* in_sizes, int n_in,
                              void* d_out, int out_size, void* d_ws, size_t ws_size,
                              hipStream_t stream) {
    const float* x  = (const float*)d_in[0];
    const float* wq = (const float*)d_in[1];
    const float* wk = (const float*)d_in[2];
    const float* wv = (const float*)d_in[3];
    const float* wo = (const float*)d_in[4];

    char* ws = (char*)d_ws;
    bf16* wqkvT = (bf16*)(ws);                    // 6291456 B
    bf16* woT   = (bf16*)(ws + 6291456);          // 2097152 B
    bf16* Qb    = (bf16*)(ws + 8388608);          // 16777216 B
    bf16* Kb    = (bf16*)(ws + 25165824);         // 16777216 B
    bf16* Vb    = (bf16*)(ws + 41943040);         // 16777216 B
    bf16* Vtb   = (bf16*)(ws + 58720256);         // 16777216 B
    bf16* ctx   = (bf16*)(ws + 75497472);         // 16777216 B
    bf16* xb    = ctx;  // x-bf16 lives in the ctx region (dead until attn writes it)

    cast_x_kernel<<<4096, 256, 0, stream>>>(x, xb);
    transpose_w_kernel<<<dim3(32, 32, 4), dim3(32, 8), 0, stream>>>(wq, wk, wv, wo, wqkvT, woT);
    gemm_kernel<0><<<1536, 256, 0, stream>>>(xb, wqkvT, Qb, Kb, Vb, 8192, 3072, 1024, 24);
    transpose_v_kernel<<<dim3(32, 64), 256, 0, stream>>>(Vb, Vtb);
    attn_kernel<<<dim3(64, 16), 256, 0, stream>>>(Qb, Kb, Vtb, ctx);
    gemm_kernel<1><<<512, 256, 0, stream>>>(ctx, woT, d_out, nullptr, nullptr, 8192, 1024, 1024, 8);
}